// Round 7
// baseline (261.813 us; speedup 1.0000x reference)
//
#include <hip/hip_runtime.h>
#include <math.h>

// Problem constants: B=64, D=128, N=500000, K+1=4096
constexpr int Bb   = 64;
constexpr int Dd   = 128;
constexpr int KP1  = 4096;
constexpr int Nrow = 500000;           // rows per bank
constexpr long NMEM = (long)Nrow * Dd; // elements per bank
constexpr int BK   = Bb * KP1;         // 262144 per score output

// streaming-score machinery
constexpr int MSLOT = 16;              // slots per row (P(overflow) ~1e-12)
constexpr int NGROUP = 31250;          // 1024-f4 groups over both banks
constexpr int GPB    = 15625;          // groups per bank (16,000,000 f4 / 1024)
constexpr long WS_NEED = (long)Nrow * 4 * (1 + MSLOT);  // cnt + entries = 34 MB

typedef float f4 __attribute__((ext_vector_type(4)));

// Output layout: [0,BK) out_image | [BK,2BK) out_gene | banks image,gene
__device__ __forceinline__ float dot8(float4 a, float4 b, float4 x0, float4 x1) {
    return a.x*x0.x + a.y*x0.y + a.z*x0.z + a.w*x0.w
         + b.x*x1.x + b.y*x1.y + b.z*x1.z + b.w*x1.w;
}

// ============ streaming-score path ============

__global__ __launch_bounds__(512) void zero_cnt(int* cnt) {
    int i = blockIdx.x * 512 + threadIdx.x;
    for (; i < Nrow; i += gridDim.x * 512) cnt[i] = 0;
}

// one thread per idx entry j; entries[r*16+c] = j  (j = b*4096+k)
__global__ __launch_bounds__(512) void build_inv(
    const int* __restrict__ idx, int* __restrict__ cnt, int* __restrict__ entries)
{
    const int j = blockIdx.x * 512 + threadIdx.x;   // grid 512x512 = 262144
    const int r = idx[j];
    const int c = atomicAdd(&cnt[r], 1);
    if (c < MSLOT) entries[r * MSLOT + c] = j;
}

// copy both banks (pure streaming) + compute raw scores from in-flight rows.
// bank0(image) rows dot gene[b] -> out_gene (out+BK); bank1(gene) -> out_image.
__global__ __launch_bounds__(512, 2) void copy_score(
    const float* __restrict__ image, const float* __restrict__ gene,
    const float* __restrict__ mem_image, const float* __restrict__ mem_gene,
    const int* __restrict__ cnt, const int* __restrict__ entries,
    float* __restrict__ out)
{
    const int tid  = threadIdx.x;
    const int half = tid >> 5;          // 0..15 (16 half-waves)
    const int lane = tid & 31;

    __shared__ f4 lxi[2048];            // image [64][32] f4  (32 KB)
    __shared__ f4 lxg[2048];            // gene  [64][32] f4  (32 KB)
    {
        const f4* gi = (const f4*)image;
        const f4* gg = (const f4*)gene;
        #pragma unroll
        for (int u = 0; u < 4; ++u) {
            lxi[u * 512 + tid] = gi[u * 512 + tid];
            lxg[u * 512 + tid] = gg[u * 512 + tid];
        }
    }
    __syncthreads();

    const f4* srcI = (const f4*)mem_image;
    const f4* srcG = (const f4*)mem_gene;
    f4* dst = (f4*)(out + 2 * BK);      // banks contiguous

    for (int G0 = blockIdx.x * 8; G0 < NGROUP; G0 += gridDim.x * 8) {
        const int gl = (NGROUP - G0 < 8) ? (NGROUP - G0) : 8;
        f4 v[16];
        // ---- issue all loads (16 in flight) ----
        #pragma unroll
        for (int q = 0; q < 8; ++q) {
            if (q < gl) {
                const int G = G0 + q;
                const f4* s = (G < GPB) ? srcI + (long)G * 1024
                                        : srcG + (long)(G - GPB) * 1024;
                v[2 * q]     = s[tid];
                v[2 * q + 1] = s[512 + tid];
            }
        }
        // ---- store + match ----
        #pragma unroll
        for (int q = 0; q < 8; ++q) {
            if (q < gl) {
                const int G = G0 + q;
                const long dbase = (long)G * 1024;
                __builtin_nontemporal_store(v[2 * q],     dst + dbase + tid);
                __builtin_nontemporal_store(v[2 * q + 1], dst + dbase + 512 + tid);

                const int bank  = (G < GPB) ? 0 : 1;
                const int rbase = (bank ? (G - GPB) : G) * 32;
                const f4* lx    = bank ? lxi : lxg;        // gene-bank rows dot image
                float* odir     = bank ? out : out + BK;   // -> out_image / out_gene
                #pragma unroll
                for (int s2 = 0; s2 < 2; ++s2) {
                    const int r = rbase + s2 * 16 + half;
                    int n = cnt[r];
                    n = (n < MSLOT) ? n : MSLOT;
                    const f4 rv = v[2 * q + s2];
                    for (int e = 0; e < n; ++e) {
                        const int j = entries[r * MSLOT + e];
                        const f4 xv = lx[(j >> 12) * 32 + lane];
                        float s = rv.x * xv.x + rv.y * xv.y + rv.z * xv.z + rv.w * xv.w;
                        s += __shfl_xor(s, 1);
                        s += __shfl_xor(s, 2);
                        s += __shfl_xor(s, 4);
                        s += __shfl_xor(s, 8);
                        s += __shfl_xor(s, 16);
                        if (lane == 0) odir[j] = s;
                    }
                }
            }
        }
    }
}

// in-place softmax over each of the 128 score rows (4096 each)
__global__ __launch_bounds__(512) void softmax_rows(float* __restrict__ out) {
    const int tid = threadIdx.x;
    f4* row = (f4*)(out + (long)blockIdx.x * KP1);
    __shared__ float red[8];

    f4 a = row[tid], b = row[tid + 512];
    float m = fmaxf(fmaxf(fmaxf(a.x, a.y), fmaxf(a.z, a.w)),
                    fmaxf(fmaxf(b.x, b.y), fmaxf(b.z, b.w)));
    #pragma unroll
    for (int off = 1; off < 64; off <<= 1) m = fmaxf(m, __shfl_xor(m, off));
    if ((tid & 63) == 0) red[tid >> 6] = m;
    __syncthreads();
    if (tid < 64) {
        float tv = (tid < 8) ? red[tid] : -INFINITY;
        #pragma unroll
        for (int off = 1; off < 8; off <<= 1) tv = fmaxf(tv, __shfl_xor(tv, off));
        if (tid == 0) red[0] = tv;
    }
    __syncthreads();
    m = red[0];
    __syncthreads();

    a.x = expf(a.x - m); a.y = expf(a.y - m); a.z = expf(a.z - m); a.w = expf(a.w - m);
    b.x = expf(b.x - m); b.y = expf(b.y - m); b.z = expf(b.z - m); b.w = expf(b.w - m);
    float sum = a.x + a.y + a.z + a.w + b.x + b.y + b.z + b.w;
    #pragma unroll
    for (int off = 1; off < 64; off <<= 1) sum += __shfl_xor(sum, off);
    if ((tid & 63) == 0) red[tid >> 6] = sum;
    __syncthreads();
    if (tid < 64) {
        float tv = (tid < 8) ? red[tid] : 0.f;
        #pragma unroll
        for (int off = 1; off < 8; off <<= 1) tv += __shfl_xor(tv, off);
        if (tid == 0) red[0] = tv;
    }
    __syncthreads();
    const float inv = 1.0f / red[0];
    a *= inv; b *= inv;
    row[tid] = a; row[tid + 512] = b;
}

// ============ fallback (proven R6) pieces ============

constexpr long HALF_F4    = NMEM / 4;
constexpr int  CHUNK_F4   = 8192;
constexpr int  FULL_PER_B = 1953;
constexpr long TAIL_BASE  = (long)FULL_PER_B * CHUNK_F4;
constexpr int  CHUNKS_PER_BANK = FULL_PER_B + 1;
constexpr int  NCHUNK     = 2 * CHUNKS_PER_BANK;

__global__ __launch_bounds__(64) void zero_ctr(unsigned* ctr) {
    if (threadIdx.x == 0) *ctr = 0u;
}

__global__ __launch_bounds__(512, 2) void fused_scores_copy(
    const float* __restrict__ image, const float* __restrict__ gene,
    const float* __restrict__ mem_image, const float* __restrict__ mem_gene,
    const int* __restrict__ idx, float* __restrict__ out, unsigned* __restrict__ ctr)
{
    const int tid = threadIdx.x;

    if (blockIdx.x < 128) {
        const int b     = blockIdx.x >> 1;
        const int which = blockIdx.x & 1;
        const float* w = which ? mem_image : mem_gene;
        const float* x = which ? gene : image;
        float* o = out + (long)which * BK + (long)b * KP1;

        __shared__ int   sidx[KP1];
        __shared__ float sv[KP1];
        __shared__ float red[8];

        {
            const int4* s4 = (const int4*)(idx + (long)b * KP1);
            int4* d4 = (int4*)sidx;
            d4[tid]       = s4[tid];
            d4[tid + 512] = s4[tid + 512];
        }
        const int lg  = tid & 15;
        const int grp = tid >> 4;
        float4 x0 = *(const float4*)(x + b * Dd + lg * 8);
        float4 x1 = *(const float4*)(x + b * Dd + lg * 8 + 4);
        __syncthreads();

        for (int j = 0; j < 128; j += 4) {
            const int k0 = grp + (j + 0) * 32;
            const int k1 = grp + (j + 1) * 32;
            const int k2 = grp + (j + 2) * 32;
            const int k3 = grp + (j + 3) * 32;
            const float4* r0 = (const float4*)(w + (long)sidx[k0] * Dd + lg * 8);
            const float4* r1 = (const float4*)(w + (long)sidx[k1] * Dd + lg * 8);
            const float4* r2 = (const float4*)(w + (long)sidx[k2] * Dd + lg * 8);
            const float4* r3 = (const float4*)(w + (long)sidx[k3] * Dd + lg * 8);
            float4 a0 = r0[0], b0 = r0[1];
            float4 a1 = r1[0], b1 = r1[1];
            float4 a2 = r2[0], b2 = r2[1];
            float4 a3 = r3[0], b3 = r3[1];
            float d0 = dot8(a0, b0, x0, x1);
            float d1 = dot8(a1, b1, x0, x1);
            float d2 = dot8(a2, b2, x0, x1);
            float d3 = dot8(a3, b3, x0, x1);
            d0 += __shfl_xor(d0, 1); d1 += __shfl_xor(d1, 1);
            d2 += __shfl_xor(d2, 1); d3 += __shfl_xor(d3, 1);
            d0 += __shfl_xor(d0, 2); d1 += __shfl_xor(d1, 2);
            d2 += __shfl_xor(d2, 2); d3 += __shfl_xor(d3, 2);
            d0 += __shfl_xor(d0, 4); d1 += __shfl_xor(d1, 4);
            d2 += __shfl_xor(d2, 4); d3 += __shfl_xor(d3, 4);
            d0 += __shfl_xor(d0, 8); d1 += __shfl_xor(d1, 8);
            d2 += __shfl_xor(d2, 8); d3 += __shfl_xor(d3, 8);
            if (lg == 0) { sv[k0] = d0; sv[k1] = d1; sv[k2] = d2; sv[k3] = d3; }
        }
        __syncthreads();

        float m = fmaxf(sv[tid], sv[tid + 512]);
        m = fmaxf(m, fmaxf(sv[tid + 1024], sv[tid + 1536]));
        m = fmaxf(m, fmaxf(sv[tid + 2048], sv[tid + 2560]));
        m = fmaxf(m, fmaxf(sv[tid + 3072], sv[tid + 3584]));
        #pragma unroll
        for (int off = 1; off < 64; off <<= 1) m = fmaxf(m, __shfl_xor(m, off));
        if ((tid & 63) == 0) red[tid >> 6] = m;
        __syncthreads();
        if (tid < 64) {
            float tv = (tid < 8) ? red[tid] : -INFINITY;
            #pragma unroll
            for (int off = 1; off < 8; off <<= 1) tv = fmaxf(tv, __shfl_xor(tv, off));
            if (tid == 0) red[0] = tv;
        }
        __syncthreads();
        m = red[0];
        __syncthreads();

        float sum = 0.f;
        #pragma unroll
        for (int r = 0; r < 8; ++r) {
            int k = tid + r * 512;
            float e = expf(sv[k] - m);
            sv[k] = e;
            sum += e;
        }
        #pragma unroll
        for (int off = 1; off < 64; off <<= 1) sum += __shfl_xor(sum, off);
        if ((tid & 63) == 0) red[tid >> 6] = sum;
        __syncthreads();
        if (tid < 64) {
            float tv = (tid < 8) ? red[tid] : 0.f;
            #pragma unroll
            for (int off = 1; off < 8; off <<= 1) tv += __shfl_xor(tv, off);
            if (tid == 0) red[0] = tv;
        }
        __syncthreads();
        const float inv = 1.0f / red[0];
        #pragma unroll
        for (int r = 0; r < 8; ++r) { int k = tid + r * 512; o[k] = sv[k] * inv; }
    }

    const f4* srcI = (const f4*)mem_image;
    const f4* srcG = (const f4*)mem_gene;
    f4* dst = (f4*)(out + 2 * BK);

    __shared__ unsigned sc;
    for (;;) {
        if (tid == 0) sc = atomicAdd(ctr, 1u);
        __syncthreads();
        const unsigned c = sc;
        __syncthreads();
        if (c >= NCHUNK) break;
        const int  bank  = (c < CHUNKS_PER_BANK) ? 0 : 1;
        const int  local = bank ? (int)(c - CHUNKS_PER_BANK) : (int)c;
        const f4*  sbank = bank ? srcG : srcI;
        const long dbank = (long)bank * HALF_F4;
        if (local < FULL_PER_B) {
            const long base = (long)local * CHUNK_F4;
            f4 v[16];
            #pragma unroll
            for (int k = 0; k < 16; ++k) v[k] = sbank[base + k * 512 + tid];
            #pragma unroll
            for (int k = 0; k < 16; ++k)
                __builtin_nontemporal_store(v[k], dst + dbank + base + k * 512 + tid);
        } else {
            f4 v0 = sbank[TAIL_BASE + tid];
            f4 v1 = sbank[TAIL_BASE + 512 + tid];
            __builtin_nontemporal_store(v0, dst + dbank + TAIL_BASE + tid);
            __builtin_nontemporal_store(v1, dst + dbank + TAIL_BASE + 512 + tid);
        }
    }
}

// momentum scatter-update (runs last)
__global__ __launch_bounds__(128) void momentum_update(
    const float* __restrict__ image, const float* __restrict__ gene,
    const float* __restrict__ mem_image, const float* __restrict__ mem_gene,
    const int* __restrict__ index, float* __restrict__ out)
{
    const int b     = blockIdx.x;
    const int which = blockIdx.y;
    const float* mem = which ? mem_gene : mem_image;
    const float* x   = which ? gene : image;
    float* o = out + 2 * BK + (long)which * NMEM;
    const long row = index[b];
    const int d = threadIdx.x;
    float p = mem[row * Dd + d] * 0.5f + x[(long)b * Dd + d] * 0.5f;
    float ss = p * p;
    #pragma unroll
    for (int off = 1; off < 64; off <<= 1) ss += __shfl_xor(ss, off);
    __shared__ float r2[2];
    if ((d & 63) == 0) r2[d >> 6] = ss;
    __syncthreads();
    const float inv = 1.0f / sqrtf(r2[0] + r2[1]);
    o[row * Dd + d] = p * inv;
}

extern "C" void kernel_launch(void* const* d_in, const int* in_sizes, int n_in,
                              void* d_out, int out_size, void* d_ws, size_t ws_size,
                              hipStream_t stream) {
    const float* image     = (const float*)d_in[0];
    const float* gene      = (const float*)d_in[1];
    const float* mem_image = (const float*)d_in[2];
    const float* mem_gene  = (const float*)d_in[3];
    const int*   index     = (const int*)d_in[4];
    const int*   idx       = (const int*)d_in[5];
    float* out = (float*)d_out;

    if ((long)ws_size >= WS_NEED) {
        int* cnt     = (int*)d_ws;
        int* entries = cnt + Nrow;
        zero_cnt<<<dim3(512), 512, 0, stream>>>(cnt);
        build_inv<<<dim3(512), 512, 0, stream>>>(idx, cnt, entries);
        copy_score<<<dim3(2048), 512, 0, stream>>>(
            image, gene, mem_image, mem_gene, cnt, entries, out);
        softmax_rows<<<dim3(128), 512, 0, stream>>>(out);
    } else {
        unsigned* ctr = (unsigned*)d_ws;
        zero_ctr<<<dim3(1), 64, 0, stream>>>(ctr);
        fused_scores_copy<<<dim3(2048), 512, 0, stream>>>(
            image, gene, mem_image, mem_gene, idx, out, ctr);
    }
    momentum_update<<<dim3(64, 2), 128, 0, stream>>>(
        image, gene, mem_image, mem_gene, index, out);
}

// Round 8
// 229.143 us; speedup vs baseline: 1.1426x; 1.1426x over previous
//
#include <hip/hip_runtime.h>
#include <math.h>

// Problem constants: B=64, D=128, N=500000, K+1=4096
constexpr int Bb   = 64;
constexpr int Dd   = 128;
constexpr int KP1  = 4096;
constexpr int Nrow = 500000;           // rows per bank
constexpr long NMEM = (long)Nrow * Dd; // elements per bank
constexpr int BK   = Bb * KP1;         // 262144 per score output

// streaming-score machinery
constexpr int MSLOT = 16;              // slots per row (P(overflow) ~1e-12; R7 passed)
constexpr int NGROUP = 31250;          // 1024-f4 groups over both banks (32 rows each)
constexpr int GPB    = 15625;          // groups per bank
constexpr int SGQ    = 8;              // groups per super-group iteration (128 KB)
constexpr int NSG    = (NGROUP + SGQ - 1) / SGQ;   // 3907
constexpr long WS_NEED = (long)Nrow * 4 * (1 + MSLOT);  // 34 MB

typedef float f4 __attribute__((ext_vector_type(4)));

// Output layout: [0,BK) out_image | [BK,2BK) out_gene | new banks (image,gene)
__device__ __forceinline__ float dot8(float4 a, float4 b, float4 x0, float4 x1) {
    return a.x*x0.x + a.y*x0.y + a.z*x0.z + a.w*x0.w
         + b.x*x1.x + b.y*x1.y + b.z*x1.z + b.w*x1.w;
}

// ============ streaming-score path ============

__global__ __launch_bounds__(512) void zero_cnt(int* cnt) {
    int i = blockIdx.x * 512 + threadIdx.x;
    for (; i < Nrow; i += gridDim.x * 512) cnt[i] = 0;
}

// one thread per idx entry j (j = b*4096+k); entries[r*16+c] = j
__global__ __launch_bounds__(512) void build_inv(
    const int* __restrict__ idx, int* __restrict__ cnt, int* __restrict__ entries)
{
    const int j = blockIdx.x * 512 + threadIdx.x;   // grid 512x512 = 262144
    const int r = idx[j];
    const int c = atomicAdd(&cnt[r], 1);
    if (c < MSLOT) entries[r * MSLOT + c] = j;
}

// Copy both banks (pure streaming) + compute raw scores from the in-flight rows.
// bank0(image) rows dot gene[b] -> out_gene; bank1(gene) rows dot image[b] -> out_image.
// Per iteration (8 groups = 256 rows = 128 KB): issue 16 v-loads + LDS-prefetch of
// cnt/e0 for all 256 rows, then stores, then match with zero exposed latency.
__global__ __launch_bounds__(512, 2) void copy_score(
    const float* __restrict__ image, const float* __restrict__ gene,
    const float* __restrict__ mem_image, const float* __restrict__ mem_gene,
    const int* __restrict__ cnt, const int* __restrict__ entries,
    float* __restrict__ out)
{
    const int tid  = threadIdx.x;
    const int half = tid >> 5;          // 0..15 half-waves
    const int lane = tid & 31;

    __shared__ f4  lxi[2048];           // image [64][32] f4  (32 KB)
    __shared__ f4  lxg[2048];           // gene  [64][32] f4  (32 KB)
    __shared__ int scnt[256];           // per-row refcount, this iteration
    __shared__ int se0[256];            // per-row slot-0 entry
    {
        const f4* gi = (const f4*)image;
        const f4* gg = (const f4*)gene;
        #pragma unroll
        for (int u = 0; u < 4; ++u) {
            lxi[u * 512 + tid] = gi[u * 512 + tid];
            lxg[u * 512 + tid] = gg[u * 512 + tid];
        }
    }
    __syncthreads();

    const f4* srcI = (const f4*)mem_image;
    const f4* srcG = (const f4*)mem_gene;
    f4* dst = (f4*)(out + 2 * BK);      // banks contiguous in out

    for (int G0 = blockIdx.x * SGQ; G0 < NGROUP; G0 += gridDim.x * SGQ) {
        const int gl = (NGROUP - G0 < SGQ) ? (NGROUP - G0) : SGQ;

        // ---- phase 0: issue streaming loads + cnt/e0 prefetch ----
        f4 v[16];
        #pragma unroll
        for (int q = 0; q < SGQ; ++q) {
            if (q < gl) {
                const int G = G0 + q;
                const f4* s = (G < GPB) ? srcI + (long)G * 1024
                                        : srcG + (long)(G - GPB) * 1024;
                v[2 * q]     = s[tid];
                v[2 * q + 1] = s[512 + tid];
            }
        }
        {
            const int slot = tid & 255;        // q = slot>>5, roff = slot&31
            const int q    = slot >> 5;
            if (q < gl) {
                const int G   = G0 + q;
                const int row = ((G < GPB) ? G : G - GPB) * 32 + (slot & 31);
                if (tid < 256) scnt[slot] = cnt[row];
                else           se0[slot]  = entries[row * MSLOT];
            }
        }

        // ---- phase 1: streaming stores ----
        #pragma unroll
        for (int q = 0; q < SGQ; ++q) {
            if (q < gl) {
                const long dbase = (long)(G0 + q) * 1024;
                __builtin_nontemporal_store(v[2 * q],     dst + dbase + tid);
                __builtin_nontemporal_store(v[2 * q + 1], dst + dbase + 512 + tid);
            }
        }
        __syncthreads();   // scnt/se0 visible

        // ---- phase 2: match (n from LDS; e0 already fetched) ----
        #pragma unroll
        for (int q = 0; q < SGQ; ++q) {
            if (q < gl) {
                const int G     = G0 + q;
                const int bank  = (G >= GPB);
                const int rbase = (bank ? G - GPB : G) * 32;
                const f4* lx    = bank ? lxi : lxg;       // gene rows dot image
                float* odir     = bank ? out : out + BK;  // -> out_image / out_gene
                #pragma unroll
                for (int s2 = 0; s2 < 2; ++s2) {
                    const int slot = q * 32 + s2 * 16 + half;
                    int n = scnt[slot];
                    if (n <= 0) continue;
                    n = (n < MSLOT) ? n : MSLOT;
                    const f4 rv = v[2 * q + s2];
                    int j = se0[slot];
                    for (int e = 0;;) {
                        const f4 xv = lx[(j >> 12) * 32 + lane];
                        float s = rv.x*xv.x + rv.y*xv.y + rv.z*xv.z + rv.w*xv.w;
                        s += __shfl_xor(s, 1);
                        s += __shfl_xor(s, 2);
                        s += __shfl_xor(s, 4);
                        s += __shfl_xor(s, 8);
                        s += __shfl_xor(s, 16);
                        if (lane == 0) odir[j] = s;
                        if (++e >= n) break;
                        j = entries[(rbase + s2 * 16 + half) * MSLOT + e];
                    }
                }
            }
        }
        __syncthreads();   // protect scnt/se0 before next iteration's prefetch
    }
}

// Epilogue: blocks [0,128) in-place row softmax; blocks [128,160) momentum update.
__global__ __launch_bounds__(512) void epilogue(
    const float* __restrict__ image, const float* __restrict__ gene,
    const float* __restrict__ mem_image, const float* __restrict__ mem_gene,
    const int* __restrict__ index, float* __restrict__ out)
{
    const int tid = threadIdx.x;

    if (blockIdx.x < 128) {
        f4* row = (f4*)(out + (long)blockIdx.x * KP1);
        __shared__ float red[8];

        f4 a = row[tid], b = row[tid + 512];
        float m = fmaxf(fmaxf(fmaxf(a.x, a.y), fmaxf(a.z, a.w)),
                        fmaxf(fmaxf(b.x, b.y), fmaxf(b.z, b.w)));
        #pragma unroll
        for (int off = 1; off < 64; off <<= 1) m = fmaxf(m, __shfl_xor(m, off));
        if ((tid & 63) == 0) red[tid >> 6] = m;
        __syncthreads();
        if (tid < 64) {
            float tv = (tid < 8) ? red[tid] : -INFINITY;
            #pragma unroll
            for (int off = 1; off < 8; off <<= 1) tv = fmaxf(tv, __shfl_xor(tv, off));
            if (tid == 0) red[0] = tv;
        }
        __syncthreads();
        m = red[0];
        __syncthreads();

        a.x = expf(a.x - m); a.y = expf(a.y - m); a.z = expf(a.z - m); a.w = expf(a.w - m);
        b.x = expf(b.x - m); b.y = expf(b.y - m); b.z = expf(b.z - m); b.w = expf(b.w - m);
        float sum = a.x + a.y + a.z + a.w + b.x + b.y + b.z + b.w;
        #pragma unroll
        for (int off = 1; off < 64; off <<= 1) sum += __shfl_xor(sum, off);
        if ((tid & 63) == 0) red[tid >> 6] = sum;
        __syncthreads();
        if (tid < 64) {
            float tv = (tid < 8) ? red[tid] : 0.f;
            #pragma unroll
            for (int off = 1; off < 8; off <<= 1) tv += __shfl_xor(tv, off);
            if (tid == 0) red[0] = tv;
        }
        __syncthreads();
        const float inv = 1.0f / red[0];
        a *= inv; b *= inv;
        row[tid] = a; row[tid + 512] = b;
        return;
    }

    // momentum: 32 blocks x 4 tasks (task = 128 threads), proven in R4
    const int task  = ((blockIdx.x - 128) << 2) | (tid >> 7);  // 0..127
    const int sub   = tid >> 7;
    const int d     = tid & 127;
    const int which = task >> 6;       // 0 -> image bank, 1 -> gene bank
    const int b     = task & 63;
    const float* mem = which ? mem_gene : mem_image;
    const float* x   = which ? gene : image;
    float* o = out + 2 * BK + (long)which * NMEM;

    const long row = index[b];
    float p = mem[row * Dd + d] * 0.5f + x[(long)b * Dd + d] * 0.5f;
    float ss = p * p;
    #pragma unroll
    for (int off = 1; off < 64; off <<= 1) ss += __shfl_xor(ss, off);
    __shared__ float r2[8];
    if ((tid & 63) == 0) r2[tid >> 6] = ss;
    __syncthreads();
    const float inv = 1.0f / sqrtf(r2[2 * sub] + r2[2 * sub + 1]);
    o[row * Dd + d] = p * inv;
}

// ============ fallback (proven R6) pieces ============

constexpr long HALF_F4    = NMEM / 4;
constexpr int  CHUNK_F4   = 8192;
constexpr int  FULL_PER_B = 1953;
constexpr long TAIL_BASE  = (long)FULL_PER_B * CHUNK_F4;
constexpr int  CHUNKS_PER_BANK = FULL_PER_B + 1;
constexpr int  NCHUNK     = 2 * CHUNKS_PER_BANK;

__global__ __launch_bounds__(64) void zero_ctr(unsigned* ctr) {
    if (threadIdx.x == 0) *ctr = 0u;
}

__global__ __launch_bounds__(512, 2) void fused_scores_copy(
    const float* __restrict__ image, const float* __restrict__ gene,
    const float* __restrict__ mem_image, const float* __restrict__ mem_gene,
    const int* __restrict__ idx, float* __restrict__ out, unsigned* __restrict__ ctr)
{
    const int tid = threadIdx.x;

    if (blockIdx.x < 128) {
        const int b     = blockIdx.x >> 1;
        const int which = blockIdx.x & 1;
        const float* w = which ? mem_image : mem_gene;
        const float* x = which ? gene : image;
        float* o = out + (long)which * BK + (long)b * KP1;

        __shared__ int   sidx[KP1];
        __shared__ float sv[KP1];
        __shared__ float red[8];
        {
            const int4* s4 = (const int4*)(idx + (long)b * KP1);
            int4* d4 = (int4*)sidx;
            d4[tid]       = s4[tid];
            d4[tid + 512] = s4[tid + 512];
        }
        const int lg  = tid & 15;
        const int grp = tid >> 4;
        float4 x0 = *(const float4*)(x + b * Dd + lg * 8);
        float4 x1 = *(const float4*)(x + b * Dd + lg * 8 + 4);
        __syncthreads();

        for (int j = 0; j < 128; j += 4) {
            const int k0 = grp + (j + 0) * 32;
            const int k1 = grp + (j + 1) * 32;
            const int k2 = grp + (j + 2) * 32;
            const int k3 = grp + (j + 3) * 32;
            const float4* r0 = (const float4*)(w + (long)sidx[k0] * Dd + lg * 8);
            const float4* r1 = (const float4*)(w + (long)sidx[k1] * Dd + lg * 8);
            const float4* r2 = (const float4*)(w + (long)sidx[k2] * Dd + lg * 8);
            const float4* r3 = (const float4*)(w + (long)sidx[k3] * Dd + lg * 8);
            float4 a0 = r0[0], b0 = r0[1];
            float4 a1 = r1[0], b1 = r1[1];
            float4 a2 = r2[0], b2 = r2[1];
            float4 a3 = r3[0], b3 = r3[1];
            float d0 = dot8(a0, b0, x0, x1);
            float d1 = dot8(a1, b1, x0, x1);
            float d2 = dot8(a2, b2, x0, x1);
            float d3 = dot8(a3, b3, x0, x1);
            d0 += __shfl_xor(d0, 1); d1 += __shfl_xor(d1, 1);
            d2 += __shfl_xor(d2, 1); d3 += __shfl_xor(d3, 1);
            d0 += __shfl_xor(d0, 2); d1 += __shfl_xor(d1, 2);
            d2 += __shfl_xor(d2, 2); d3 += __shfl_xor(d3, 2);
            d0 += __shfl_xor(d0, 4); d1 += __shfl_xor(d1, 4);
            d2 += __shfl_xor(d2, 4); d3 += __shfl_xor(d3, 4);
            d0 += __shfl_xor(d0, 8); d1 += __shfl_xor(d1, 8);
            d2 += __shfl_xor(d2, 8); d3 += __shfl_xor(d3, 8);
            if (lg == 0) { sv[k0] = d0; sv[k1] = d1; sv[k2] = d2; sv[k3] = d3; }
        }
        __syncthreads();

        float m = fmaxf(sv[tid], sv[tid + 512]);
        m = fmaxf(m, fmaxf(sv[tid + 1024], sv[tid + 1536]));
        m = fmaxf(m, fmaxf(sv[tid + 2048], sv[tid + 2560]));
        m = fmaxf(m, fmaxf(sv[tid + 3072], sv[tid + 3584]));
        #pragma unroll
        for (int off = 1; off < 64; off <<= 1) m = fmaxf(m, __shfl_xor(m, off));
        if ((tid & 63) == 0) red[tid >> 6] = m;
        __syncthreads();
        if (tid < 64) {
            float tv = (tid < 8) ? red[tid] : -INFINITY;
            #pragma unroll
            for (int off = 1; off < 8; off <<= 1) tv = fmaxf(tv, __shfl_xor(tv, off));
            if (tid == 0) red[0] = tv;
        }
        __syncthreads();
        m = red[0];
        __syncthreads();

        float sum = 0.f;
        #pragma unroll
        for (int r = 0; r < 8; ++r) {
            int k = tid + r * 512;
            float e = expf(sv[k] - m);
            sv[k] = e;
            sum += e;
        }
        #pragma unroll
        for (int off = 1; off < 64; off <<= 1) sum += __shfl_xor(sum, off);
        if ((tid & 63) == 0) red[tid >> 6] = sum;
        __syncthreads();
        if (tid < 64) {
            float tv = (tid < 8) ? red[tid] : 0.f;
            #pragma unroll
            for (int off = 1; off < 8; off <<= 1) tv += __shfl_xor(tv, off);
            if (tid == 0) red[0] = tv;
        }
        __syncthreads();
        const float inv = 1.0f / red[0];
        #pragma unroll
        for (int r = 0; r < 8; ++r) { int k = tid + r * 512; o[k] = sv[k] * inv; }
    }

    const f4* srcI = (const f4*)mem_image;
    const f4* srcG = (const f4*)mem_gene;
    f4* dst = (f4*)(out + 2 * BK);

    __shared__ unsigned sc;
    for (;;) {
        if (tid == 0) sc = atomicAdd(ctr, 1u);
        __syncthreads();
        const unsigned c = sc;
        __syncthreads();
        if (c >= NCHUNK) break;
        const int  bank  = (c < CHUNKS_PER_BANK) ? 0 : 1;
        const int  local = bank ? (int)(c - CHUNKS_PER_BANK) : (int)c;
        const f4*  sbank = bank ? srcG : srcI;
        const long dbank = (long)bank * HALF_F4;
        if (local < FULL_PER_B) {
            const long base = (long)local * CHUNK_F4;
            f4 v[16];
            #pragma unroll
            for (int k = 0; k < 16; ++k) v[k] = sbank[base + k * 512 + tid];
            #pragma unroll
            for (int k = 0; k < 16; ++k)
                __builtin_nontemporal_store(v[k], dst + dbank + base + k * 512 + tid);
        } else {
            f4 v0 = sbank[TAIL_BASE + tid];
            f4 v1 = sbank[TAIL_BASE + 512 + tid];
            __builtin_nontemporal_store(v0, dst + dbank + TAIL_BASE + tid);
            __builtin_nontemporal_store(v1, dst + dbank + TAIL_BASE + 512 + tid);
        }
    }
}

__global__ __launch_bounds__(128) void momentum_update(
    const float* __restrict__ image, const float* __restrict__ gene,
    const float* __restrict__ mem_image, const float* __restrict__ mem_gene,
    const int* __restrict__ index, float* __restrict__ out)
{
    const int b     = blockIdx.x;
    const int which = blockIdx.y;
    const float* mem = which ? mem_gene : mem_image;
    const float* x   = which ? gene : image;
    float* o = out + 2 * BK + (long)which * NMEM;
    const long row = index[b];
    const int d = threadIdx.x;
    float p = mem[row * Dd + d] * 0.5f + x[(long)b * Dd + d] * 0.5f;
    float ss = p * p;
    #pragma unroll
    for (int off = 1; off < 64; off <<= 1) ss += __shfl_xor(ss, off);
    __shared__ float r2[2];
    if ((d & 63) == 0) r2[d >> 6] = ss;
    __syncthreads();
    const float inv = 1.0f / sqrtf(r2[0] + r2[1]);
    o[row * Dd + d] = p * inv;
}

extern "C" void kernel_launch(void* const* d_in, const int* in_sizes, int n_in,
                              void* d_out, int out_size, void* d_ws, size_t ws_size,
                              hipStream_t stream) {
    const float* image     = (const float*)d_in[0];
    const float* gene      = (const float*)d_in[1];
    const float* mem_image = (const float*)d_in[2];
    const float* mem_gene  = (const float*)d_in[3];
    const int*   index     = (const int*)d_in[4];
    const int*   idx       = (const int*)d_in[5];
    float* out = (float*)d_out;

    if ((long)ws_size >= WS_NEED) {
        int* cnt     = (int*)d_ws;
        int* entries = cnt + Nrow;
        zero_cnt<<<dim3(1024), 512, 0, stream>>>(cnt);
        build_inv<<<dim3(512), 512, 0, stream>>>(idx, cnt, entries);
        copy_score<<<dim3(1954), 512, 0, stream>>>(
            image, gene, mem_image, mem_gene, cnt, entries, out);
        epilogue<<<dim3(160), 512, 0, stream>>>(
            image, gene, mem_image, mem_gene, index, out);
    } else {
        unsigned* ctr = (unsigned*)d_ws;
        zero_ctr<<<dim3(1), 64, 0, stream>>>(ctr);
        fused_scores_copy<<<dim3(2048), 512, 0, stream>>>(
            image, gene, mem_image, mem_gene, idx, out, ctr);
        momentum_update<<<dim3(64, 2), 128, 0, stream>>>(
            image, gene, mem_image, mem_gene, index, out);
    }
}